// Round 6
// baseline (159.061 us; speedup 1.0000x reference)
//
#include <hip/hip_runtime.h>

#define IN_F 8192
#define OUT_F 8192
#define BLOCK 256
#define KPT (IN_F / 4 / BLOCK)     // 8 float4 per thread per row stream
#define ROWS_PER_BLOCK 4
#define GRID (OUT_F / ROWS_PER_BLOCK)   // 2048 blocks = 8 per CU, one generation

typedef float v4f __attribute__((ext_vector_type(4)));

__global__ __launch_bounds__(BLOCK) void snn_fused_kernel(
    const float* __restrict__ x,        // [IN_F] spike_input
    const float* __restrict__ syn,      // [OUT_F, IN_F] synapse_states
    const float* __restrict__ mp,       // [OUT_F] membrane_potential
    const float* __restrict__ at,       // [OUT_F] adaptive_threshold
    const float* __restrict__ trace,    // [OUT_F, IN_F] eligibility_trace
    float* __restrict__ spikes_out,     // [OUT_F]
    float* __restrict__ vmem_out,       // [OUT_F]
    float* __restrict__ trace_out,      // [OUT_F, IN_F]
    float* __restrict__ thr_out)        // [OUT_F]
{
    const int tid = threadIdx.x;
    const v4f* __restrict__ x4 = reinterpret_cast<const v4f*>(x);

    // double-buffered cross-wave partials: no trailing barrier needed per row
    __shared__ float wsum[2][BLOCK / 64];

    #pragma unroll 1
    for (int r = 0; r < ROWS_PER_BLOCK; ++r) {
        const int o = blockIdx.x * ROWS_PER_BLOCK + r;

        const v4f* __restrict__ syn4 = reinterpret_cast<const v4f*>(syn + (size_t)o * IN_F);
        const v4f* __restrict__ tr4  = reinterpret_cast<const v4f*>(trace + (size_t)o * IN_F);

        // ---- interleaved dual read streams (syn + trace advance in lockstep)
        v4f s[KPT], t[KPT], xv[KPT];
        #pragma unroll
        for (int k = 0; k < KPT; ++k) {
            const int i = tid + k * BLOCK;
            s[k] = syn4[i];                 // HBM/L3 stream 1
            t[k] = tr4[i];                  // HBM/L3 stream 2
            xv[k] = x4[i];                  // L1-resident
        }

        // ---- masked row-sum: current = sum_i (syn[o,i] > 50) * x[i]
        float partial = 0.0f;
        #pragma unroll
        for (int k = 0; k < KPT; ++k) {
            partial += (s[k].x > 50.0f ? xv[k].x : 0.0f);
            partial += (s[k].y > 50.0f ? xv[k].y : 0.0f);
            partial += (s[k].z > 50.0f ? xv[k].z : 0.0f);
            partial += (s[k].w > 50.0f ? xv[k].w : 0.0f);
        }
        #pragma unroll
        for (int off = 32; off > 0; off >>= 1)
            partial += __shfl_down(partial, off, 64);

        if ((tid & 63) == 0) wsum[r & 1][tid >> 6] = partial;
        __syncthreads();                    // the ONLY barrier per row

        // every thread computes the scalar update (wave-uniform, cheap)
        const float cur = wsum[r & 1][0] + wsum[r & 1][1]
                        + wsum[r & 1][2] + wsum[r & 1][3];
        const float v  = mp[o] * 0.8f + cur;
        const float a  = at[o];
        const float sp = (v >= a) ? 1.0f : 0.0f;
        if (tid == 0) {
            spikes_out[o] = sp;
            vmem_out[o]   = v * (1.0f - sp) * 0.2f;
            thr_out[o]    = fminf(fmaxf(a + (sp - 0.05f) * 0.1f, 0.5f), 10.0f);
        }

        // ---- trace update: pure register -> HBM write burst
        const float sp3 = sp * 3.0f;
        v4f* out4 = reinterpret_cast<v4f*>(trace_out + (size_t)o * IN_F);
        #pragma unroll
        for (int k = 0; k < KPT; ++k) {
            v4f rr;
            rr.x = fminf(fmaxf(t[k].x * 0.7f + sp3 * xv[k].x, 0.0f), 10.0f);
            rr.y = fminf(fmaxf(t[k].y * 0.7f + sp3 * xv[k].y, 0.0f), 10.0f);
            rr.z = fminf(fmaxf(t[k].z * 0.7f + sp3 * xv[k].z, 0.0f), 10.0f);
            rr.w = fminf(fmaxf(t[k].w * 0.7f + sp3 * xv[k].w, 0.0f), 10.0f);
            out4[tid + k * BLOCK] = rr;
        }
    }
}

extern "C" void kernel_launch(void* const* d_in, const int* in_sizes, int n_in,
                              void* d_out, int out_size, void* d_ws, size_t ws_size,
                              hipStream_t stream) {
    const float* x     = (const float*)d_in[0];  // spike_input [8192]
    const float* syn   = (const float*)d_in[1];  // synapse_states [8192,8192]
    const float* mp    = (const float*)d_in[2];  // membrane_potential [8192]
    const float* at    = (const float*)d_in[3];  // adaptive_threshold [8192]
    const float* trace = (const float*)d_in[4];  // eligibility_trace [8192,8192]

    float* out        = (float*)d_out;
    float* spikes_out = out;                                            // [8192]
    float* vmem_out   = out + OUT_F;                                    // [8192]
    float* trace_out  = out + 2 * (size_t)OUT_F;                        // [8192*8192]
    float* thr_out    = out + 2 * (size_t)OUT_F + (size_t)OUT_F * IN_F; // [8192]

    snn_fused_kernel<<<GRID, BLOCK, 0, stream>>>(
        x, syn, mp, at, trace, spikes_out, vmem_out, trace_out, thr_out);
}

// Round 7
// 141.555 us; speedup vs baseline: 1.1237x; 1.1237x over previous
//
#include <hip/hip_runtime.h>

#define IN_F 8192
#define OUT_F 8192
#define BLOCK 256
#define KPT (IN_F / 4 / BLOCK)   // 8 float4 per thread per stream

typedef float v4f __attribute__((ext_vector_type(4)));

// Block per row, fully register-staged. All 24 loads per thread (syn, trace, x)
// issue before the reduce and are PINNED by an asm use-fence so the compiler
// cannot sink the trace loads past the barrier (R5's VGPR=40 showed it did).
// Phase 2 is a pure register->HBM write burst.
__global__ __launch_bounds__(BLOCK, 4) void snn_fused_kernel(
    const float* __restrict__ x,        // [IN_F] spike_input
    const float* __restrict__ syn,      // [OUT_F, IN_F] synapse_states
    const float* __restrict__ mp,       // [OUT_F] membrane_potential
    const float* __restrict__ at,       // [OUT_F] adaptive_threshold
    const float* __restrict__ trace,    // [OUT_F, IN_F] eligibility_trace
    float* __restrict__ spikes_out,     // [OUT_F]
    float* __restrict__ vmem_out,       // [OUT_F]
    float* __restrict__ trace_out,      // [OUT_F, IN_F]
    float* __restrict__ thr_out)        // [OUT_F]
{
    const int o   = blockIdx.x;
    const int tid = threadIdx.x;

    const v4f* __restrict__ syn4 = reinterpret_cast<const v4f*>(syn + (size_t)o * IN_F);
    const v4f* __restrict__ tr4  = reinterpret_cast<const v4f*>(trace + (size_t)o * IN_F);
    const v4f* __restrict__ x4   = reinterpret_cast<const v4f*>(x);

    // ---- issue ALL loads up front: 24 independent 16B loads in flight/thread
    v4f s[KPT], t[KPT], xv[KPT];
    #pragma unroll
    for (int k = 0; k < KPT; ++k) {
        const int i = tid + k * BLOCK;
        s[k]  = syn4[i];    // HBM/L3 stream 1
        t[k]  = tr4[i];     // HBM/L3 stream 2
        xv[k] = x4[i];      // L1-resident
    }
    // pin: all values must be materialized in registers HERE (no sinking)
    #pragma unroll
    for (int k = 0; k < KPT; ++k)
        asm volatile("" :: "v"(s[k]), "v"(t[k]), "v"(xv[k]));

    // ---- masked row-sum: current = sum_i (syn[o,i] > 50) * x[i]
    float partial = 0.0f;
    #pragma unroll
    for (int k = 0; k < KPT; ++k) {
        partial += (s[k].x > 50.0f ? xv[k].x : 0.0f);
        partial += (s[k].y > 50.0f ? xv[k].y : 0.0f);
        partial += (s[k].z > 50.0f ? xv[k].z : 0.0f);
        partial += (s[k].w > 50.0f ? xv[k].w : 0.0f);
    }
    #pragma unroll
    for (int off = 32; off > 0; off >>= 1)
        partial += __shfl_down(partial, off, 64);

    __shared__ float wsum[BLOCK / 64];
    if ((tid & 63) == 0) wsum[tid >> 6] = partial;
    __syncthreads();                       // the only barrier

    // every thread computes the scalar LIF update itself (broadcast LDS reads)
    const float cur = wsum[0] + wsum[1] + wsum[2] + wsum[3];
    const float v   = mp[o] * 0.8f + cur;
    const float a   = at[o];
    const float sp  = (v >= a) ? 1.0f : 0.0f;
    if (tid == 0) {
        spikes_out[o] = sp;
        vmem_out[o]   = v * (1.0f - sp) * 0.2f;
        thr_out[o]    = fminf(fmaxf(a + (sp - 0.05f) * 0.1f, 0.5f), 10.0f);
    }

    // ---- phase 2: pure register -> HBM write burst (zero loads)
    const float sp3 = sp * 3.0f;
    v4f* out4 = reinterpret_cast<v4f*>(trace_out + (size_t)o * IN_F);
    #pragma unroll
    for (int k = 0; k < KPT; ++k) {
        v4f r;
        r.x = fminf(fmaxf(t[k].x * 0.7f + sp3 * xv[k].x, 0.0f), 10.0f);
        r.y = fminf(fmaxf(t[k].y * 0.7f + sp3 * xv[k].y, 0.0f), 10.0f);
        r.z = fminf(fmaxf(t[k].z * 0.7f + sp3 * xv[k].z, 0.0f), 10.0f);
        r.w = fminf(fmaxf(t[k].w * 0.7f + sp3 * xv[k].w, 0.0f), 10.0f);
        out4[tid + k * BLOCK] = r;
    }
}

extern "C" void kernel_launch(void* const* d_in, const int* in_sizes, int n_in,
                              void* d_out, int out_size, void* d_ws, size_t ws_size,
                              hipStream_t stream) {
    const float* x     = (const float*)d_in[0];  // spike_input [8192]
    const float* syn   = (const float*)d_in[1];  // synapse_states [8192,8192]
    const float* mp    = (const float*)d_in[2];  // membrane_potential [8192]
    const float* at    = (const float*)d_in[3];  // adaptive_threshold [8192]
    const float* trace = (const float*)d_in[4];  // eligibility_trace [8192,8192]

    float* out        = (float*)d_out;
    float* spikes_out = out;                                            // [8192]
    float* vmem_out   = out + OUT_F;                                    // [8192]
    float* trace_out  = out + 2 * (size_t)OUT_F;                        // [8192*8192]
    float* thr_out    = out + 2 * (size_t)OUT_F + (size_t)OUT_F * IN_F; // [8192]

    snn_fused_kernel<<<OUT_F, BLOCK, 0, stream>>>(
        x, syn, mp, at, trace, spikes_out, vmem_out, trace_out, thr_out);
}